// Round 4
// baseline (1209.282 us; speedup 1.0000x reference)
//
#include <hip/hip_runtime.h>
#include <float.h>

#define NSEG 4096
#define CAP 2048   // max edges/segment held in LDS (binomial(1M,1/4096) max ~330)

// ---- segment boundaries: segs[b] = first edge index with batch >= b ----
__global__ void seg_bounds(const int* __restrict__ batch, int* __restrict__ segs, int E) {
  int b = blockIdx.x * blockDim.x + threadIdx.x;
  if (b > NSEG) return;
  int lo = 0, hi = E;
  while (lo < hi) { int mid = (lo + hi) >> 1; if (batch[mid] < b) lo = mid + 1; else hi = mid; }
  segs[b] = lo;
}

// Y = X @ W (+bias for blockIdx.y==1); X: nrows x 128, W: 128 x 128 row-major.
// 256 threads, 64 rows/block, 4x8 micro-tile (32 FMA/k). X tile in LDS pitch 132
// (ty-stride 528 = 16 mod 32 -> free 2-way alias, 0 conflicts measured in R2).
// W streamed from global through an explicit 2-chunk register pipeline: while
// computing chunk kc (2 k-steps, 64 FMA), the 4 float4 loads of chunk kc+2 are
// in flight -> wait is vmcnt(4), never a full drain. launch_bounds(256,4)
// pins VGPR<=128 so the LDS-capped 4 blocks/CU stay resident.
__global__ __launch_bounds__(256, 4) void proj_gemm(
    const float* __restrict__ Xj, const float* __restrict__ Wj,
    const float* __restrict__ Xi, const float* __restrict__ Wi,
    const float* __restrict__ bias,
    float* __restrict__ Yj, float* __restrict__ Yi, int nrows) {
  const int which = blockIdx.y;
  const float* X = which ? Xi : Xj;
  const float* W = which ? Wi : Wj;
  float* Y = which ? Yi : Yj;

  __shared__ float xs[64 * 132];
  const int tid = threadIdx.x;
  const long base = (long)blockIdx.x * (64 * 128);
  const long total = (long)nrows * 128;
  #pragma unroll
  for (int i = 0; i < 8; ++i) {
    int idx = tid + i * 256;
    int row = idx >> 5;
    int col4 = idx & 31;
    long ge = base + (long)idx * 4;
    float4 v = make_float4(0.f, 0.f, 0.f, 0.f);
    if (ge + 3 < total) v = *(const float4*)(X + ge);
    float* dst = xs + row * 132 + col4 * 4;
    *(float2*)(dst) = make_float2(v.x, v.y);
    *(float2*)(dst + 2) = make_float2(v.z, v.w);
  }
  __syncthreads();

  const int ty = tid >> 4;   // 0..15 -> rows ty*4..+3
  const int tx = tid & 15;   // 0..15 -> cols tx*8..+7 (contiguous 32B of W per k)
  const int r0 = ty * 4;
  const int c0 = tx * 8;

  float acc[4][8] = {};
  const float* Wp = W + c0;

  // W register pipeline: wbuf[buf][kk][half]
  float4 wbuf[2][2][2];
  wbuf[0][0][0] = *(const float4*)(Wp);
  wbuf[0][0][1] = *(const float4*)(Wp + 4);
  wbuf[0][1][0] = *(const float4*)(Wp + 128);
  wbuf[0][1][1] = *(const float4*)(Wp + 128 + 4);

  for (int kc = 0; kc < 128; kc += 2) {
    const int cur = (kc >> 1) & 1;
    const int nxt = cur ^ 1;
    if (kc + 2 < 128) {
      const float* Wn = Wp + (kc + 2) * 128;
      wbuf[nxt][0][0] = *(const float4*)(Wn);
      wbuf[nxt][0][1] = *(const float4*)(Wn + 4);
      wbuf[nxt][1][0] = *(const float4*)(Wn + 128);
      wbuf[nxt][1][1] = *(const float4*)(Wn + 128 + 4);
    }
    #pragma unroll
    for (int kk = 0; kk < 2; ++kk) {
      const int k = kc + kk;
      float xv[4];
      #pragma unroll
      for (int j = 0; j < 4; ++j) xv[j] = xs[(r0 + j) * 132 + k];
      const float4 w0 = wbuf[cur][kk][0];
      const float4 w1 = wbuf[cur][kk][1];
      #pragma unroll
      for (int r = 0; r < 4; ++r) {
        acc[r][0] += xv[r] * w0.x; acc[r][1] += xv[r] * w0.y;
        acc[r][2] += xv[r] * w0.z; acc[r][3] += xv[r] * w0.w;
        acc[r][4] += xv[r] * w1.x; acc[r][5] += xv[r] * w1.y;
        acc[r][6] += xv[r] * w1.z; acc[r][7] += xv[r] * w1.w;
      }
    }
  }

  float4 b0 = make_float4(0.f, 0.f, 0.f, 0.f), b1 = b0;
  if (which) { b0 = *(const float4*)(bias + c0); b1 = *(const float4*)(bias + c0 + 4); }
  const long rowBase = (long)blockIdx.x * 64 + r0;
  #pragma unroll
  for (int r = 0; r < 4; ++r) {
    long row = rowBase + r;
    if (row < nrows) {
      *(float4*)(Y + row * 128 + c0) =
          make_float4(acc[r][0] + b0.x, acc[r][1] + b0.y, acc[r][2] + b0.z, acc[r][3] + b0.w);
      *(float4*)(Y + row * 128 + c0 + 4) =
          make_float4(acc[r][4] + b1.x, acc[r][5] + b1.y, acc[r][6] + b1.z, acc[r][7] + b1.w);
    }
  }
}

// One block per segment. Phase 1: alpha per edge (half-wave/edge, dual-edge
// unrolled -> 4 gathers in flight per wave). Phase 2-4: block softmax. No atomics.
__global__ __launch_bounds__(256) void seg_softmax(
    const float* __restrict__ xjp, const float* __restrict__ xip,
    const int* __restrict__ ei, const int* __restrict__ segs,
    const float* __restrict__ mlpW, const float* __restrict__ prelu_w,
    const float* __restrict__ mlp_b, float* __restrict__ out, int E) {
  const int start = segs[blockIdx.x];
  const int end = segs[blockIdx.x + 1];
  const int cnt = end - start;
  if (cnt <= 0) return;

  __shared__ float aS[CAP];
  __shared__ float red[8];

  const int tid = threadIdx.x;
  const int lane = tid & 63;
  const int sl = lane & 31;          // lane within half-wave
  const int slot = tid >> 5;         // 8 half-wave edge slots per block
  const int wid = tid >> 6;

  const float4 w = *(const float4*)(mlpW + sl * 4);
  const float pw = prelu_w[0];
  const float mb = mlp_b[0];
  const bool useLds = (cnt <= CAP);

  // ---- phase 1: alpha ----
  for (int e = start + slot; e < end; e += 16) {
    int e2 = e + 8;
    bool v2 = (e2 < end);
    int s1 = ei[e], d1 = ei[E + e];
    int s2 = v2 ? ei[e2] : s1;
    int d2 = v2 ? ei[E + e2] : d1;
    float4 a1 = *(const float4*)(xjp + (long)s1 * 128 + sl * 4);
    float4 b1 = *(const float4*)(xip + (long)d1 * 128 + sl * 4);
    float4 a2 = *(const float4*)(xjp + (long)s2 * 128 + sl * 4);
    float4 b2 = *(const float4*)(xip + (long)d2 * 128 + sl * 4);

    float h0 = a1.x + b1.x, h1 = a1.y + b1.y, h2 = a1.z + b1.z, h3 = a1.w + b1.w;
    h0 = h0 >= 0.f ? h0 : pw * h0; h1 = h1 >= 0.f ? h1 : pw * h1;
    h2 = h2 >= 0.f ? h2 : pw * h2; h3 = h3 >= 0.f ? h3 : pw * h3;
    float p1 = h0 * w.x + h1 * w.y + h2 * w.z + h3 * w.w;

    float g0 = a2.x + b2.x, g1 = a2.y + b2.y, g2 = a2.z + b2.z, g3 = a2.w + b2.w;
    g0 = g0 >= 0.f ? g0 : pw * g0; g1 = g1 >= 0.f ? g1 : pw * g1;
    g2 = g2 >= 0.f ? g2 : pw * g2; g3 = g3 >= 0.f ? g3 : pw * g3;
    float p2 = g0 * w.x + g1 * w.y + g2 * w.z + g3 * w.w;

    #pragma unroll
    for (int off = 1; off < 32; off <<= 1) {
      p1 += __shfl_xor(p1, off, 64);
      p2 += __shfl_xor(p2, off, 64);
    }
    if (sl == 0) {
      float av1 = p1 + mb;
      if (useLds) aS[e - start] = av1; else out[e] = av1;
      if (v2) {
        float av2 = p2 + mb;
        if (useLds) aS[e2 - start] = av2; else out[e2] = av2;
      }
    }
  }
  __syncthreads();

  // ---- phase 2: block max ----
  float m = -FLT_MAX;
  if (useLds) { for (int i = tid; i < cnt; i += 256) m = fmaxf(m, aS[i]); }
  else        { for (int i = tid; i < cnt; i += 256) m = fmaxf(m, out[start + i]); }
  #pragma unroll
  for (int off = 1; off < 64; off <<= 1) m = fmaxf(m, __shfl_xor(m, off, 64));
  if (lane == 0) red[wid] = m;
  __syncthreads();
  m = fmaxf(fmaxf(red[0], red[1]), fmaxf(red[2], red[3]));

  // ---- phase 3: exp + block sum ----
  float s = 0.f;
  if (useLds) {
    for (int i = tid; i < cnt; i += 256) { float x = expf(aS[i] - m); aS[i] = x; s += x; }
  } else {
    for (int i = tid; i < cnt; i += 256) { float x = expf(out[start + i] - m); out[start + i] = x; s += x; }
  }
  #pragma unroll
  for (int off = 1; off < 64; off <<= 1) s += __shfl_xor(s, off, 64);
  if (lane == 0) red[4 + wid] = s;
  __syncthreads();
  s = (red[4] + red[5]) + (red[6] + red[7]);

  // ---- phase 4: normalize + write ----
  const float inv = 1.0f / (s + 1e-16f);
  if (useLds) { for (int i = tid; i < cnt; i += 256) out[start + i] = aS[i] * inv; }
  else        { for (int i = tid; i < cnt; i += 256) out[start + i] *= inv; }
}

extern "C" void kernel_launch(void* const* d_in, const int* in_sizes, int n_in,
                              void* d_out, int out_size, void* d_ws, size_t ws_size,
                              hipStream_t stream) {
  const float* x_j      = (const float*)d_in[0];
  const float* x_i      = (const float*)d_in[1];
  const int*   edge_idx = (const int*)d_in[2];
  const int*   batch    = (const int*)d_in[3];
  const float* w_j      = (const float*)d_in[4];
  const float* w_i      = (const float*)d_in[5];
  const float* bias     = (const float*)d_in[6];
  const float* prelu_w  = (const float*)d_in[7];
  const float* mlp_W    = (const float*)d_in[8];
  const float* mlp_b    = (const float*)d_in[9];
  const int nnodes = in_sizes[0] / 128;
  const int E = in_sizes[3];

  float* xjp = (float*)d_ws;
  float* xip = xjp + (size_t)nnodes * 128;
  int* segs  = (int*)(xip + (size_t)nnodes * 128);

  hipLaunchKernelGGL(seg_bounds, dim3((NSEG + 1 + 255) / 256), dim3(256), 0, stream,
                     batch, segs, E);

  int gblocks = (nnodes + 63) / 64;
  hipLaunchKernelGGL(proj_gemm, dim3(gblocks, 2), dim3(256), 0, stream,
                     x_j, w_j, x_i, w_i, bias, xjp, xip, nnodes);

  hipLaunchKernelGGL(seg_softmax, dim3(NSEG), dim3(256), 0, stream,
                     xjp, xip, edge_idx, segs, mlp_W, prelu_w, mlp_b,
                     (float*)d_out, E);
}

// Round 5
// 1039.927 us; speedup vs baseline: 1.1629x; 1.1629x over previous
//
#include <hip/hip_runtime.h>
#include <float.h>

#define NSEG 4096
#define CAP 2048   // max edges/segment held in LDS (binomial(1M,1/4096) max ~330)

// ---- segment boundaries: segs[b] = first edge index with batch >= b ----
__global__ void seg_bounds(const int* __restrict__ batch, int* __restrict__ segs, int E) {
  int b = blockIdx.x * blockDim.x + threadIdx.x;
  if (b > NSEG) return;
  int lo = 0, hi = E;
  while (lo < hi) { int mid = (lo + hi) >> 1; if (batch[mid] < b) lo = mid + 1; else hi = mid; }
  segs[b] = lo;
}

// Y = X @ W (+bias for blockIdx.y==1); X: nrows x 128, W: 128 x 128 row-major.
// 256 threads, 64 rows/block, 4x8 micro-tile (32 FMA/k).
// X tile in LDS pitch 132; per 4-k phase each thread does 4 ds_read_b128
// (rows contiguous in k, 16B-aligned: 528B row stride). W streamed via a
// STATIC 2-buffer pipeline (A,B = 4 k-steps each, named variables only --
// round 4 showed dynamic indexing scratch-spills): while computing A's
// 128 FMA cycles, B's 8 float4 loads are in flight (distance ~4 k-steps).
// Tail prefetches clamp k to stay in-bounds; values are never consumed.
__global__ __launch_bounds__(256) void proj_gemm(
    const float* __restrict__ Xj, const float* __restrict__ Wj,
    const float* __restrict__ Xi, const float* __restrict__ Wi,
    const float* __restrict__ bias,
    float* __restrict__ Yj, float* __restrict__ Yi, int nrows) {
  const int which = blockIdx.y;
  const float* X = which ? Xi : Xj;
  const float* W = which ? Wi : Wj;
  float* Y = which ? Yi : Yj;

  __shared__ float xs[64 * 132];
  const int tid = threadIdx.x;
  const long base = (long)blockIdx.x * (64 * 128);
  const long total = (long)nrows * 128;
  #pragma unroll
  for (int i = 0; i < 8; ++i) {
    int idx = tid + i * 256;
    int row = idx >> 5;
    int col4 = idx & 31;
    long ge = base + (long)idx * 4;
    float4 v = make_float4(0.f, 0.f, 0.f, 0.f);
    if (ge + 3 < total) v = *(const float4*)(X + ge);
    float* dst = xs + row * 132 + col4 * 4;
    *(float2*)(dst) = make_float2(v.x, v.y);
    *(float2*)(dst + 2) = make_float2(v.z, v.w);
  }
  __syncthreads();

  const int ty = tid >> 4;   // rows ty*4..+3
  const int tx = tid & 15;   // cols tx*8..+7 (one contiguous 32B W region)
  const int r0 = ty * 4;
  const int c0 = tx * 8;

  float acc[4][8] = {};
  const float* Wp = W + c0;
  const float* xrow0 = xs + (r0 + 0) * 132;
  const float* xrow1 = xs + (r0 + 1) * 132;
  const float* xrow2 = xs + (r0 + 2) * 132;
  const float* xrow3 = xs + (r0 + 3) * 132;

  // 4-k-step FMA phase using 8 named float4 W regs + 4 b128 X reads.
#define PHASE(kbase, W0a, W0b, W1a, W1b, W2a, W2b, W3a, W3b)                 \
  {                                                                          \
    float4 x0 = *(const float4*)(xrow0 + (kbase));                           \
    float4 x1 = *(const float4*)(xrow1 + (kbase));                           \
    float4 x2 = *(const float4*)(xrow2 + (kbase));                           \
    float4 x3 = *(const float4*)(xrow3 + (kbase));                           \
    const float xv0[4] = {x0.x, x1.x, x2.x, x3.x};                           \
    const float xv1[4] = {x0.y, x1.y, x2.y, x3.y};                           \
    const float xv2[4] = {x0.z, x1.z, x2.z, x3.z};                           \
    const float xv3[4] = {x0.w, x1.w, x2.w, x3.w};                           \
    _Pragma("unroll")                                                        \
    for (int r = 0; r < 4; ++r) {                                            \
      acc[r][0] += xv0[r] * W0a.x; acc[r][1] += xv0[r] * W0a.y;              \
      acc[r][2] += xv0[r] * W0a.z; acc[r][3] += xv0[r] * W0a.w;              \
      acc[r][4] += xv0[r] * W0b.x; acc[r][5] += xv0[r] * W0b.y;              \
      acc[r][6] += xv0[r] * W0b.z; acc[r][7] += xv0[r] * W0b.w;              \
      acc[r][0] += xv1[r] * W1a.x; acc[r][1] += xv1[r] * W1a.y;              \
      acc[r][2] += xv1[r] * W1a.z; acc[r][3] += xv1[r] * W1a.w;              \
      acc[r][4] += xv1[r] * W1b.x; acc[r][5] += xv1[r] * W1b.y;              \
      acc[r][6] += xv1[r] * W1b.z; acc[r][7] += xv1[r] * W1b.w;              \
      acc[r][0] += xv2[r] * W2a.x; acc[r][1] += xv2[r] * W2a.y;              \
      acc[r][2] += xv2[r] * W2a.z; acc[r][3] += xv2[r] * W2a.w;              \
      acc[r][4] += xv2[r] * W2b.x; acc[r][5] += xv2[r] * W2b.y;              \
      acc[r][6] += xv2[r] * W2b.z; acc[r][7] += xv2[r] * W2b.w;              \
      acc[r][0] += xv3[r] * W3a.x; acc[r][1] += xv3[r] * W3a.y;              \
      acc[r][2] += xv3[r] * W3a.z; acc[r][3] += xv3[r] * W3a.w;              \
      acc[r][4] += xv3[r] * W3b.x; acc[r][5] += xv3[r] * W3b.y;              \
      acc[r][6] += xv3[r] * W3b.z; acc[r][7] += xv3[r] * W3b.w;              \
    }                                                                        \
  }

#define LOADW(kbase, W0a, W0b, W1a, W1b, W2a, W2b, W3a, W3b)                 \
  {                                                                          \
    const float* wq = Wp + (long)(kbase) * 128;                              \
    W0a = *(const float4*)(wq);           W0b = *(const float4*)(wq + 4);    \
    W1a = *(const float4*)(wq + 128);     W1b = *(const float4*)(wq + 132);  \
    W2a = *(const float4*)(wq + 256);     W2b = *(const float4*)(wq + 260);  \
    W3a = *(const float4*)(wq + 384);     W3b = *(const float4*)(wq + 388);  \
  }

  float4 A0a, A0b, A1a, A1b, A2a, A2b, A3a, A3b;
  float4 B0a, B0b, B1a, B1b, B2a, B2b, B3a, B3b;
  LOADW(0, A0a, A0b, A1a, A1b, A2a, A2b, A3a, A3b);
  LOADW(4, B0a, B0b, B1a, B1b, B2a, B2b, B3a, B3b);

  for (int kc = 0; kc < 128; kc += 8) {
    PHASE(kc, A0a, A0b, A1a, A1b, A2a, A2b, A3a, A3b);
    {  // refill A with k = kc+8 (clamped at tail; clamped values unused)
      int kn = (kc + 8 < 128) ? kc + 8 : 120;
      LOADW(kn, A0a, A0b, A1a, A1b, A2a, A2b, A3a, A3b);
    }
    PHASE(kc + 4, B0a, B0b, B1a, B1b, B2a, B2b, B3a, B3b);
    {  // refill B with k = kc+12 (clamped at tail)
      int kn = (kc + 12 < 128) ? kc + 12 : 120;
      LOADW(kn, B0a, B0b, B1a, B1b, B2a, B2b, B3a, B3b);
    }
  }
#undef PHASE
#undef LOADW

  float4 b0 = make_float4(0.f, 0.f, 0.f, 0.f), b1 = b0;
  if (which) { b0 = *(const float4*)(bias + c0); b1 = *(const float4*)(bias + c0 + 4); }
  const long rowBase = (long)blockIdx.x * 64 + r0;
  #pragma unroll
  for (int r = 0; r < 4; ++r) {
    long row = rowBase + r;
    if (row < nrows) {
      *(float4*)(Y + row * 128 + c0) =
          make_float4(acc[r][0] + b0.x, acc[r][1] + b0.y, acc[r][2] + b0.z, acc[r][3] + b0.w);
      *(float4*)(Y + row * 128 + c0 + 4) =
          make_float4(acc[r][4] + b1.x, acc[r][5] + b1.y, acc[r][6] + b1.z, acc[r][7] + b1.w);
    }
  }
}

// One block per segment. Phase 1: alpha per edge, half-wave per edge,
// 4-edge unroll -> 8 gathers in flight per half-wave slot. No atomics.
__global__ __launch_bounds__(256) void seg_softmax(
    const float* __restrict__ xjp, const float* __restrict__ xip,
    const int* __restrict__ ei, const int* __restrict__ segs,
    const float* __restrict__ mlpW, const float* __restrict__ prelu_w,
    const float* __restrict__ mlp_b, float* __restrict__ out, int E) {
  const int start = segs[blockIdx.x];
  const int end = segs[blockIdx.x + 1];
  const int cnt = end - start;
  if (cnt <= 0) return;

  __shared__ float aS[CAP];
  __shared__ float red[8];

  const int tid = threadIdx.x;
  const int lane = tid & 63;
  const int sl = lane & 31;          // lane within half-wave
  const int slot = tid >> 5;         // 8 half-wave edge slots per block
  const int wid = tid >> 6;

  const float4 w = *(const float4*)(mlpW + sl * 4);
  const float pw = prelu_w[0];
  const float mb = mlp_b[0];
  const bool useLds = (cnt <= CAP);

  // ---- phase 1: alpha (4 edges per slot iteration) ----
  for (int e = start + slot; e < end; e += 32) {
    int e2 = e + 8, e3 = e + 16, e4 = e + 24;
    bool v2 = (e2 < end), v3 = (e3 < end), v4 = (e4 < end);
    int s1 = ei[e],             d1 = ei[E + e];
    int s2 = v2 ? ei[e2] : s1,  d2 = v2 ? ei[E + e2] : d1;
    int s3 = v3 ? ei[e3] : s1,  d3 = v3 ? ei[E + e3] : d1;
    int s4 = v4 ? ei[e4] : s1,  d4 = v4 ? ei[E + e4] : d1;
    float4 a1 = *(const float4*)(xjp + (long)s1 * 128 + sl * 4);
    float4 b1 = *(const float4*)(xip + (long)d1 * 128 + sl * 4);
    float4 a2 = *(const float4*)(xjp + (long)s2 * 128 + sl * 4);
    float4 b2 = *(const float4*)(xip + (long)d2 * 128 + sl * 4);
    float4 a3 = *(const float4*)(xjp + (long)s3 * 128 + sl * 4);
    float4 b3 = *(const float4*)(xip + (long)d3 * 128 + sl * 4);
    float4 a4 = *(const float4*)(xjp + (long)s4 * 128 + sl * 4);
    float4 b4 = *(const float4*)(xip + (long)d4 * 128 + sl * 4);

    float p1, p2, p3, p4;
    {
      float h0 = a1.x + b1.x, h1 = a1.y + b1.y, h2 = a1.z + b1.z, h3 = a1.w + b1.w;
      h0 = h0 >= 0.f ? h0 : pw * h0; h1 = h1 >= 0.f ? h1 : pw * h1;
      h2 = h2 >= 0.f ? h2 : pw * h2; h3 = h3 >= 0.f ? h3 : pw * h3;
      p1 = h0 * w.x + h1 * w.y + h2 * w.z + h3 * w.w;
    }
    {
      float h0 = a2.x + b2.x, h1 = a2.y + b2.y, h2 = a2.z + b2.z, h3 = a2.w + b2.w;
      h0 = h0 >= 0.f ? h0 : pw * h0; h1 = h1 >= 0.f ? h1 : pw * h1;
      h2 = h2 >= 0.f ? h2 : pw * h2; h3 = h3 >= 0.f ? h3 : pw * h3;
      p2 = h0 * w.x + h1 * w.y + h2 * w.z + h3 * w.w;
    }
    {
      float h0 = a3.x + b3.x, h1 = a3.y + b3.y, h2 = a3.z + b3.z, h3 = a3.w + b3.w;
      h0 = h0 >= 0.f ? h0 : pw * h0; h1 = h1 >= 0.f ? h1 : pw * h1;
      h2 = h2 >= 0.f ? h2 : pw * h2; h3 = h3 >= 0.f ? h3 : pw * h3;
      p3 = h0 * w.x + h1 * w.y + h2 * w.z + h3 * w.w;
    }
    {
      float h0 = a4.x + b4.x, h1 = a4.y + b4.y, h2 = a4.z + b4.z, h3 = a4.w + b4.w;
      h0 = h0 >= 0.f ? h0 : pw * h0; h1 = h1 >= 0.f ? h1 : pw * h1;
      h2 = h2 >= 0.f ? h2 : pw * h2; h3 = h3 >= 0.f ? h3 : pw * h3;
      p4 = h0 * w.x + h1 * w.y + h2 * w.z + h3 * w.w;
    }
    #pragma unroll
    for (int off = 1; off < 32; off <<= 1) {
      p1 += __shfl_xor(p1, off, 64);
      p2 += __shfl_xor(p2, off, 64);
      p3 += __shfl_xor(p3, off, 64);
      p4 += __shfl_xor(p4, off, 64);
    }
    if (sl == 0) {
      if (useLds) {
        aS[e - start] = p1 + mb;
        if (v2) aS[e2 - start] = p2 + mb;
        if (v3) aS[e3 - start] = p3 + mb;
        if (v4) aS[e4 - start] = p4 + mb;
      } else {
        out[e] = p1 + mb;
        if (v2) out[e2] = p2 + mb;
        if (v3) out[e3] = p3 + mb;
        if (v4) out[e4] = p4 + mb;
      }
    }
  }
  __syncthreads();

  // ---- phase 2: block max ----
  float m = -FLT_MAX;
  if (useLds) { for (int i = tid; i < cnt; i += 256) m = fmaxf(m, aS[i]); }
  else        { for (int i = tid; i < cnt; i += 256) m = fmaxf(m, out[start + i]); }
  #pragma unroll
  for (int off = 1; off < 64; off <<= 1) m = fmaxf(m, __shfl_xor(m, off, 64));
  if (lane == 0) red[wid] = m;
  __syncthreads();
  m = fmaxf(fmaxf(red[0], red[1]), fmaxf(red[2], red[3]));

  // ---- phase 3: exp + block sum ----
  float s = 0.f;
  if (useLds) {
    for (int i = tid; i < cnt; i += 256) { float x = expf(aS[i] - m); aS[i] = x; s += x; }
  } else {
    for (int i = tid; i < cnt; i += 256) { float x = expf(out[start + i] - m); out[start + i] = x; s += x; }
  }
  #pragma unroll
  for (int off = 1; off < 64; off <<= 1) s += __shfl_xor(s, off, 64);
  if (lane == 0) red[4 + wid] = s;
  __syncthreads();
  s = (red[4] + red[5]) + (red[6] + red[7]);

  // ---- phase 4: normalize + write ----
  const float inv = 1.0f / (s + 1e-16f);
  if (useLds) { for (int i = tid; i < cnt; i += 256) out[start + i] = aS[i] * inv; }
  else        { for (int i = tid; i < cnt; i += 256) out[start + i] *= inv; }
}

extern "C" void kernel_launch(void* const* d_in, const int* in_sizes, int n_in,
                              void* d_out, int out_size, void* d_ws, size_t ws_size,
                              hipStream_t stream) {
  const float* x_j      = (const float*)d_in[0];
  const float* x_i      = (const float*)d_in[1];
  const int*   edge_idx = (const int*)d_in[2];
  const int*   batch    = (const int*)d_in[3];
  const float* w_j      = (const float*)d_in[4];
  const float* w_i      = (const float*)d_in[5];
  const float* bias     = (const float*)d_in[6];
  const float* prelu_w  = (const float*)d_in[7];
  const float* mlp_W    = (const float*)d_in[8];
  const float* mlp_b    = (const float*)d_in[9];
  const int nnodes = in_sizes[0] / 128;
  const int E = in_sizes[3];

  float* xjp = (float*)d_ws;
  float* xip = xjp + (size_t)nnodes * 128;
  int* segs  = (int*)(xip + (size_t)nnodes * 128);

  hipLaunchKernelGGL(seg_bounds, dim3((NSEG + 1 + 255) / 256), dim3(256), 0, stream,
                     batch, segs, E);

  int gblocks = (nnodes + 63) / 64;
  hipLaunchKernelGGL(proj_gemm, dim3(gblocks, 2), dim3(256), 0, stream,
                     x_j, w_j, x_i, w_i, bias, xjp, xip, nnodes);

  hipLaunchKernelGGL(seg_softmax, dim3(NSEG), dim3(256), 0, stream,
                     xjp, xip, edge_idx, segs, mlp_W, prelu_w, mlp_b,
                     (float*)d_out, E);
}

// Round 6
// 472.505 us; speedup vs baseline: 2.5593x; 2.2009x over previous
//
#include <hip/hip_runtime.h>
#include <float.h>

#define NSEG 4096
#define CAP 2048   // max edges/segment held in LDS (binomial(1M,1/4096) max ~330)

// ---- segment boundaries: segs[b] = first edge index with batch >= b ----
__global__ void seg_bounds(const int* __restrict__ batch, int* __restrict__ segs, int E) {
  int b = blockIdx.x * blockDim.x + threadIdx.x;
  if (b > NSEG) return;
  int lo = 0, hi = E;
  while (lo < hi) { int mid = (lo + hi) >> 1; if (batch[mid] < b) lo = mid + 1; else hi = mid; }
  segs[b] = lo;
}

// Y = X @ W (+bias for blockIdx.y==1); X: nrows x 128, W: 128 x 128 row-major.
// R2 inner loop (best measured schedule: compiler-scheduled, scalar xs reads,
// dual 16B W loads) but 32-row tiles: LDS 16.9KB -> 8 blocks/CU (wave-capped)
// = 32 waves/CU = 100% occupancy for TLP latency hiding. 2x8 micro-tile,
// acc=16 regs -> ~40 VGPR, launch_bounds(256,8) pins 8 waves/SIMD.
// xs bank pattern: ty-stride 264 words = 8 mod 32 -> 4 distinct banks,
// 16-lane broadcasts, 0 conflicts.
__global__ __launch_bounds__(256, 8) void proj_gemm(
    const float* __restrict__ Xj, const float* __restrict__ Wj,
    const float* __restrict__ Xi, const float* __restrict__ Wi,
    const float* __restrict__ bias,
    float* __restrict__ Yj, float* __restrict__ Yi, int nrows) {
  const int which = blockIdx.y;
  const float* X = which ? Xi : Xj;
  const float* W = which ? Wi : Wj;
  float* Y = which ? Yi : Yj;

  __shared__ float xs[32 * 132];
  const int tid = threadIdx.x;
  const long base = (long)blockIdx.x * (32 * 128);
  const long total = (long)nrows * 128;
  // stage 32x128 X tile (1024 float4, 4 per thread)
  #pragma unroll
  for (int i = 0; i < 4; ++i) {
    int idx = tid + i * 256;
    int row = idx >> 5;          // 32 float4 per row
    int col4 = idx & 31;
    long ge = base + (long)idx * 4;
    float4 v = make_float4(0.f, 0.f, 0.f, 0.f);
    if (ge + 3 < total) v = *(const float4*)(X + ge);
    float* dst = xs + row * 132 + col4 * 4;
    *(float2*)(dst) = make_float2(v.x, v.y);
    *(float2*)(dst + 2) = make_float2(v.z, v.w);
  }
  __syncthreads();

  const int ty = tid >> 4;   // 0..15 -> rows ty*2..+1
  const int tx = tid & 15;   // cols tx*4..+3 and 64+tx*4..+3
  const int r0 = ty * 2;
  const int c0 = tx * 4;

  float acc0[2][4] = {};
  float acc1[2][4] = {};
  const float* Wc = W + c0;
  #pragma unroll 4
  for (int k = 0; k < 128; ++k) {
    float4 w0 = *(const float4*)(Wc + k * 128);
    float4 w1 = *(const float4*)(Wc + k * 128 + 64);
    float xv[2];
    #pragma unroll
    for (int r = 0; r < 2; ++r) xv[r] = xs[(r0 + r) * 132 + k];
    #pragma unroll
    for (int r = 0; r < 2; ++r) {
      acc0[r][0] += xv[r] * w0.x; acc0[r][1] += xv[r] * w0.y;
      acc0[r][2] += xv[r] * w0.z; acc0[r][3] += xv[r] * w0.w;
      acc1[r][0] += xv[r] * w1.x; acc1[r][1] += xv[r] * w1.y;
      acc1[r][2] += xv[r] * w1.z; acc1[r][3] += xv[r] * w1.w;
    }
  }

  float4 b0 = make_float4(0.f, 0.f, 0.f, 0.f), b1 = b0;
  if (which) { b0 = *(const float4*)(bias + c0); b1 = *(const float4*)(bias + 64 + c0); }
  const long rowBase = (long)blockIdx.x * 32 + r0;
  #pragma unroll
  for (int r = 0; r < 2; ++r) {
    long row = rowBase + r;
    if (row < nrows) {
      *(float4*)(Y + row * 128 + c0) =
          make_float4(acc0[r][0] + b0.x, acc0[r][1] + b0.y, acc0[r][2] + b0.z, acc0[r][3] + b0.w);
      *(float4*)(Y + row * 128 + 64 + c0) =
          make_float4(acc1[r][0] + b1.x, acc1[r][1] + b1.y, acc1[r][2] + b1.z, acc1[r][3] + b1.w);
    }
  }
}

// One block per segment. Phase 1: alpha per edge, half-wave per edge,
// 4-edge unroll -> 8 gathers in flight per half-wave slot. No atomics.
__global__ __launch_bounds__(256) void seg_softmax(
    const float* __restrict__ xjp, const float* __restrict__ xip,
    const int* __restrict__ ei, const int* __restrict__ segs,
    const float* __restrict__ mlpW, const float* __restrict__ prelu_w,
    const float* __restrict__ mlp_b, float* __restrict__ out, int E) {
  const int start = segs[blockIdx.x];
  const int end = segs[blockIdx.x + 1];
  const int cnt = end - start;
  if (cnt <= 0) return;

  __shared__ float aS[CAP];
  __shared__ float red[8];

  const int tid = threadIdx.x;
  const int lane = tid & 63;
  const int sl = lane & 31;          // lane within half-wave
  const int slot = tid >> 5;         // 8 half-wave edge slots per block
  const int wid = tid >> 6;

  const float4 w = *(const float4*)(mlpW + sl * 4);
  const float pw = prelu_w[0];
  const float mb = mlp_b[0];
  const bool useLds = (cnt <= CAP);

  // ---- phase 1: alpha (4 edges per slot iteration) ----
  for (int e = start + slot; e < end; e += 32) {
    int e2 = e + 8, e3 = e + 16, e4 = e + 24;
    bool v2 = (e2 < end), v3 = (e3 < end), v4 = (e4 < end);
    int s1 = ei[e],             d1 = ei[E + e];
    int s2 = v2 ? ei[e2] : s1,  d2 = v2 ? ei[E + e2] : d1;
    int s3 = v3 ? ei[e3] : s1,  d3 = v3 ? ei[E + e3] : d1;
    int s4 = v4 ? ei[e4] : s1,  d4 = v4 ? ei[E + e4] : d1;
    float4 a1 = *(const float4*)(xjp + (long)s1 * 128 + sl * 4);
    float4 b1 = *(const float4*)(xip + (long)d1 * 128 + sl * 4);
    float4 a2 = *(const float4*)(xjp + (long)s2 * 128 + sl * 4);
    float4 b2 = *(const float4*)(xip + (long)d2 * 128 + sl * 4);
    float4 a3 = *(const float4*)(xjp + (long)s3 * 128 + sl * 4);
    float4 b3 = *(const float4*)(xip + (long)d3 * 128 + sl * 4);
    float4 a4 = *(const float4*)(xjp + (long)s4 * 128 + sl * 4);
    float4 b4 = *(const float4*)(xip + (long)d4 * 128 + sl * 4);

    float p1, p2, p3, p4;
    {
      float h0 = a1.x + b1.x, h1 = a1.y + b1.y, h2 = a1.z + b1.z, h3 = a1.w + b1.w;
      h0 = h0 >= 0.f ? h0 : pw * h0; h1 = h1 >= 0.f ? h1 : pw * h1;
      h2 = h2 >= 0.f ? h2 : pw * h2; h3 = h3 >= 0.f ? h3 : pw * h3;
      p1 = h0 * w.x + h1 * w.y + h2 * w.z + h3 * w.w;
    }
    {
      float h0 = a2.x + b2.x, h1 = a2.y + b2.y, h2 = a2.z + b2.z, h3 = a2.w + b2.w;
      h0 = h0 >= 0.f ? h0 : pw * h0; h1 = h1 >= 0.f ? h1 : pw * h1;
      h2 = h2 >= 0.f ? h2 : pw * h2; h3 = h3 >= 0.f ? h3 : pw * h3;
      p2 = h0 * w.x + h1 * w.y + h2 * w.z + h3 * w.w;
    }
    {
      float h0 = a3.x + b3.x, h1 = a3.y + b3.y, h2 = a3.z + b3.z, h3 = a3.w + b3.w;
      h0 = h0 >= 0.f ? h0 : pw * h0; h1 = h1 >= 0.f ? h1 : pw * h1;
      h2 = h2 >= 0.f ? h2 : pw * h2; h3 = h3 >= 0.f ? h3 : pw * h3;
      p3 = h0 * w.x + h1 * w.y + h2 * w.z + h3 * w.w;
    }
    {
      float h0 = a4.x + b4.x, h1 = a4.y + b4.y, h2 = a4.z + b4.z, h3 = a4.w + b4.w;
      h0 = h0 >= 0.f ? h0 : pw * h0; h1 = h1 >= 0.f ? h1 : pw * h1;
      h2 = h2 >= 0.f ? h2 : pw * h2; h3 = h3 >= 0.f ? h3 : pw * h3;
      p4 = h0 * w.x + h1 * w.y + h2 * w.z + h3 * w.w;
    }
    #pragma unroll
    for (int off = 1; off < 32; off <<= 1) {
      p1 += __shfl_xor(p1, off, 64);
      p2 += __shfl_xor(p2, off, 64);
      p3 += __shfl_xor(p3, off, 64);
      p4 += __shfl_xor(p4, off, 64);
    }
    if (sl == 0) {
      if (useLds) {
        aS[e - start] = p1 + mb;
        if (v2) aS[e2 - start] = p2 + mb;
        if (v3) aS[e3 - start] = p3 + mb;
        if (v4) aS[e4 - start] = p4 + mb;
      } else {
        out[e] = p1 + mb;
        if (v2) out[e2] = p2 + mb;
        if (v3) out[e3] = p3 + mb;
        if (v4) out[e4] = p4 + mb;
      }
    }
  }
  __syncthreads();

  // ---- phase 2: block max ----
  float m = -FLT_MAX;
  if (useLds) { for (int i = tid; i < cnt; i += 256) m = fmaxf(m, aS[i]); }
  else        { for (int i = tid; i < cnt; i += 256) m = fmaxf(m, out[start + i]); }
  #pragma unroll
  for (int off = 1; off < 64; off <<= 1) m = fmaxf(m, __shfl_xor(m, off, 64));
  if (lane == 0) red[wid] = m;
  __syncthreads();
  m = fmaxf(fmaxf(red[0], red[1]), fmaxf(red[2], red[3]));

  // ---- phase 3: exp + block sum ----
  float s = 0.f;
  if (useLds) {
    for (int i = tid; i < cnt; i += 256) { float x = expf(aS[i] - m); aS[i] = x; s += x; }
  } else {
    for (int i = tid; i < cnt; i += 256) { float x = expf(out[start + i] - m); out[start + i] = x; s += x; }
  }
  #pragma unroll
  for (int off = 1; off < 64; off <<= 1) s += __shfl_xor(s, off, 64);
  if (lane == 0) red[4 + wid] = s;
  __syncthreads();
  s = (red[4] + red[5]) + (red[6] + red[7]);

  // ---- phase 4: normalize + write ----
  const float inv = 1.0f / (s + 1e-16f);
  if (useLds) { for (int i = tid; i < cnt; i += 256) out[start + i] = aS[i] * inv; }
  else        { for (int i = tid; i < cnt; i += 256) out[start + i] *= inv; }
}

extern "C" void kernel_launch(void* const* d_in, const int* in_sizes, int n_in,
                              void* d_out, int out_size, void* d_ws, size_t ws_size,
                              hipStream_t stream) {
  const float* x_j      = (const float*)d_in[0];
  const float* x_i      = (const float*)d_in[1];
  const int*   edge_idx = (const int*)d_in[2];
  const int*   batch    = (const int*)d_in[3];
  const float* w_j      = (const float*)d_in[4];
  const float* w_i      = (const float*)d_in[5];
  const float* bias     = (const float*)d_in[6];
  const float* prelu_w  = (const float*)d_in[7];
  const float* mlp_W    = (const float*)d_in[8];
  const float* mlp_b    = (const float*)d_in[9];
  const int nnodes = in_sizes[0] / 128;
  const int E = in_sizes[3];

  float* xjp = (float*)d_ws;
  float* xip = xjp + (size_t)nnodes * 128;
  int* segs  = (int*)(xip + (size_t)nnodes * 128);

  hipLaunchKernelGGL(seg_bounds, dim3((NSEG + 1 + 255) / 256), dim3(256), 0, stream,
                     batch, segs, E);

  int gblocks = (nnodes + 31) / 32;
  hipLaunchKernelGGL(proj_gemm, dim3(gblocks, 2), dim3(256), 0, stream,
                     x_j, w_j, x_i, w_i, bias, xjp, xip, nnodes);

  hipLaunchKernelGGL(seg_softmax, dim3(NSEG), dim3(256), 0, stream,
                     xjp, xip, edge_idx, segs, mlp_W, prelu_w, mlp_b,
                     (float*)d_out, E);
}

// Round 7
// 322.770 us; speedup vs baseline: 3.7466x; 1.4639x over previous
//
#include <hip/hip_runtime.h>
#include <hip/hip_fp16.h>
#include <float.h>

#define NSEG 4096
#define CAP 2048   // max edges/segment held in LDS (max segment count ~330)

// ---- segment boundaries: segs[b] = first edge index with batch >= b ----
__global__ void seg_bounds(const int* __restrict__ batch, int* __restrict__ segs, int E) {
  int b = blockIdx.x * blockDim.x + threadIdx.x;
  if (b > NSEG) return;
  int lo = 0, hi = E;
  while (lo < hi) { int mid = (lo + hi) >> 1; if (batch[mid] < b) lo = mid + 1; else hi = mid; }
  segs[b] = lo;
}

// Y = fp16(X @ W (+bias for blockIdx.y==1)); X: nrows x 128 fp32, W: 128x128.
// EXACT R2 structure (best measured: 148us, VALUBusy 35%, 0 conflicts):
// 256 threads, 64-row tile, 4x8 micro-tile, scalar xs reads, dual 16B W loads,
// compiler-scheduled (R3-R5 proved manual ILP restructuring regresses).
// Only the epilogue changed: pack to __half2 -> halves WRITE_SIZE and halves
// the downstream gather bytes in seg_softmax.
__global__ __launch_bounds__(256) void proj_gemm(
    const float* __restrict__ Xj, const float* __restrict__ Wj,
    const float* __restrict__ Xi, const float* __restrict__ Wi,
    const float* __restrict__ bias,
    __half* __restrict__ Yj, __half* __restrict__ Yi, int nrows) {
  const int which = blockIdx.y;
  const float* X = which ? Xi : Xj;
  const float* W = which ? Wi : Wj;
  __half* Y = which ? Yi : Yj;

  __shared__ float xs[64 * 132];
  const int tid = threadIdx.x;
  const long base = (long)blockIdx.x * (64 * 128);
  const long total = (long)nrows * 128;
  #pragma unroll
  for (int i = 0; i < 8; ++i) {
    int idx = tid + i * 256;
    int row = idx >> 5;
    int col4 = idx & 31;
    long ge = base + (long)idx * 4;
    float4 v = make_float4(0.f, 0.f, 0.f, 0.f);
    if (ge + 3 < total) v = *(const float4*)(X + ge);
    float* dst = xs + row * 132 + col4 * 4;
    *(float2*)(dst) = make_float2(v.x, v.y);
    *(float2*)(dst + 2) = make_float2(v.z, v.w);
  }
  __syncthreads();

  const int ty = tid >> 4;   // rows ty*4..+3
  const int tx = tid & 15;   // cols tx*4..+3 and 64+tx*4..+3
  const int r0 = ty * 4;
  const int c0 = tx * 4;

  float acc0[4][4] = {};
  float acc1[4][4] = {};
  const float* Wc = W + c0;
  #pragma unroll 4
  for (int k = 0; k < 128; ++k) {
    float4 w0 = *(const float4*)(Wc + k * 128);
    float4 w1 = *(const float4*)(Wc + k * 128 + 64);
    float xv[4];
    #pragma unroll
    for (int r = 0; r < 4; ++r) xv[r] = xs[(r0 + r) * 132 + k];
    #pragma unroll
    for (int r = 0; r < 4; ++r) {
      acc0[r][0] += xv[r] * w0.x; acc0[r][1] += xv[r] * w0.y;
      acc0[r][2] += xv[r] * w0.z; acc0[r][3] += xv[r] * w0.w;
      acc1[r][0] += xv[r] * w1.x; acc1[r][1] += xv[r] * w1.y;
      acc1[r][2] += xv[r] * w1.z; acc1[r][3] += xv[r] * w1.w;
    }
  }

  float4 b0 = make_float4(0.f, 0.f, 0.f, 0.f), b1 = b0;
  if (which) { b0 = *(const float4*)(bias + c0); b1 = *(const float4*)(bias + 64 + c0); }
  const long rowBase = (long)blockIdx.x * 64 + r0;
  #pragma unroll
  for (int r = 0; r < 4; ++r) {
    long row = rowBase + r;
    if (row < nrows) {
      __half2 p0 = __floats2half2_rn(acc0[r][0] + b0.x, acc0[r][1] + b0.y);
      __half2 p1 = __floats2half2_rn(acc0[r][2] + b0.z, acc0[r][3] + b0.w);
      __half2 q0 = __floats2half2_rn(acc1[r][0] + b1.x, acc1[r][1] + b1.y);
      __half2 q1 = __floats2half2_rn(acc1[r][2] + b1.z, acc1[r][3] + b1.w);
      uint2 u;
      u.x = *(unsigned int*)&p0; u.y = *(unsigned int*)&p1;
      *(uint2*)(Y + row * 128 + c0) = u;
      u.x = *(unsigned int*)&q0; u.y = *(unsigned int*)&q1;
      *(uint2*)(Y + row * 128 + 64 + c0) = u;
    }
  }
}

// One block per segment. Phase 1: alpha per edge, half-wave per edge,
// 4-edge unroll -> 8 gathers in flight per slot. Rows are fp16 (256B each,
// uint2 per lane) -> half the gather bytes of the fp32 version. No atomics.
__global__ __launch_bounds__(256) void seg_softmax(
    const __half* __restrict__ xjp, const __half* __restrict__ xip,
    const int* __restrict__ ei, const int* __restrict__ segs,
    const float* __restrict__ mlpW, const float* __restrict__ prelu_w,
    const float* __restrict__ mlp_b, float* __restrict__ out, int E) {
  const int start = segs[blockIdx.x];
  const int end = segs[blockIdx.x + 1];
  const int cnt = end - start;
  if (cnt <= 0) return;

  __shared__ float aS[CAP];
  __shared__ float red[8];

  const int tid = threadIdx.x;
  const int lane = tid & 63;
  const int sl = lane & 31;          // lane within half-wave
  const int slot = tid >> 5;         // 8 half-wave edge slots per block
  const int wid = tid >> 6;

  const float4 w = *(const float4*)(mlpW + sl * 4);
  const float pw = prelu_w[0];
  const float mb = mlp_b[0];
  const bool useLds = (cnt <= CAP);

#define GATHER4(node, arr, f01, f23)                                       \
  {                                                                        \
    uint2 u = *(const uint2*)((arr) + (long)(node) * 128 + sl * 4);        \
    f01 = __half22float2(*(__half2*)&u.x);                                 \
    f23 = __half22float2(*(__half2*)&u.y);                                 \
  }

  // ---- phase 1: alpha (4 edges per slot iteration) ----
  for (int e = start + slot; e < end; e += 32) {
    int e2 = e + 8, e3 = e + 16, e4 = e + 24;
    bool v2 = (e2 < end), v3 = (e3 < end), v4 = (e4 < end);
    int s1 = ei[e],             d1 = ei[E + e];
    int s2 = v2 ? ei[e2] : s1,  d2 = v2 ? ei[E + e2] : d1;
    int s3 = v3 ? ei[e3] : s1,  d3 = v3 ? ei[E + e3] : d1;
    int s4 = v4 ? ei[e4] : s1,  d4 = v4 ? ei[E + e4] : d1;

    float2 a1lo, a1hi, b1lo, b1hi, a2lo, a2hi, b2lo, b2hi;
    float2 a3lo, a3hi, b3lo, b3hi, a4lo, a4hi, b4lo, b4hi;
    GATHER4(s1, xjp, a1lo, a1hi); GATHER4(d1, xip, b1lo, b1hi);
    GATHER4(s2, xjp, a2lo, a2hi); GATHER4(d2, xip, b2lo, b2hi);
    GATHER4(s3, xjp, a3lo, a3hi); GATHER4(d3, xip, b3lo, b3hi);
    GATHER4(s4, xjp, a4lo, a4hi); GATHER4(d4, xip, b4lo, b4hi);

    float p1, p2, p3, p4;
#define ALPHA(alo, ahi, blo, bhi, p)                                        \
    {                                                                       \
      float h0 = alo.x + blo.x, h1 = alo.y + blo.y;                         \
      float h2 = ahi.x + bhi.x, h3 = ahi.y + bhi.y;                         \
      h0 = h0 >= 0.f ? h0 : pw * h0; h1 = h1 >= 0.f ? h1 : pw * h1;         \
      h2 = h2 >= 0.f ? h2 : pw * h2; h3 = h3 >= 0.f ? h3 : pw * h3;         \
      p = h0 * w.x + h1 * w.y + h2 * w.z + h3 * w.w;                        \
    }
    ALPHA(a1lo, a1hi, b1lo, b1hi, p1);
    ALPHA(a2lo, a2hi, b2lo, b2hi, p2);
    ALPHA(a3lo, a3hi, b3lo, b3hi, p3);
    ALPHA(a4lo, a4hi, b4lo, b4hi, p4);
#undef ALPHA

    #pragma unroll
    for (int off = 1; off < 32; off <<= 1) {
      p1 += __shfl_xor(p1, off, 64);
      p2 += __shfl_xor(p2, off, 64);
      p3 += __shfl_xor(p3, off, 64);
      p4 += __shfl_xor(p4, off, 64);
    }
    if (sl == 0) {
      if (useLds) {
        aS[e - start] = p1 + mb;
        if (v2) aS[e2 - start] = p2 + mb;
        if (v3) aS[e3 - start] = p3 + mb;
        if (v4) aS[e4 - start] = p4 + mb;
      } else {
        out[e] = p1 + mb;
        if (v2) out[e2] = p2 + mb;
        if (v3) out[e3] = p3 + mb;
        if (v4) out[e4] = p4 + mb;
      }
    }
  }
#undef GATHER4
  __syncthreads();

  // ---- phase 2: block max ----
  float m = -FLT_MAX;
  if (useLds) { for (int i = tid; i < cnt; i += 256) m = fmaxf(m, aS[i]); }
  else        { for (int i = tid; i < cnt; i += 256) m = fmaxf(m, out[start + i]); }
  #pragma unroll
  for (int off = 1; off < 64; off <<= 1) m = fmaxf(m, __shfl_xor(m, off, 64));
  if (lane == 0) red[wid] = m;
  __syncthreads();
  m = fmaxf(fmaxf(red[0], red[1]), fmaxf(red[2], red[3]));

  // ---- phase 3: exp + block sum ----
  float s = 0.f;
  if (useLds) {
    for (int i = tid; i < cnt; i += 256) { float x = expf(aS[i] - m); aS[i] = x; s += x; }
  } else {
    for (int i = tid; i < cnt; i += 256) { float x = expf(out[start + i] - m); out[start + i] = x; s += x; }
  }
  #pragma unroll
  for (int off = 1; off < 64; off <<= 1) s += __shfl_xor(s, off, 64);
  if (lane == 0) red[4 + wid] = s;
  __syncthreads();
  s = (red[4] + red[5]) + (red[6] + red[7]);

  // ---- phase 4: normalize + write ----
  const float inv = 1.0f / (s + 1e-16f);
  if (useLds) { for (int i = tid; i < cnt; i += 256) out[start + i] = aS[i] * inv; }
  else        { for (int i = tid; i < cnt; i += 256) out[start + i] *= inv; }
}

extern "C" void kernel_launch(void* const* d_in, const int* in_sizes, int n_in,
                              void* d_out, int out_size, void* d_ws, size_t ws_size,
                              hipStream_t stream) {
  const float* x_j      = (const float*)d_in[0];
  const float* x_i      = (const float*)d_in[1];
  const int*   edge_idx = (const int*)d_in[2];
  const int*   batch    = (const int*)d_in[3];
  const float* w_j      = (const float*)d_in[4];
  const float* w_i      = (const float*)d_in[5];
  const float* bias     = (const float*)d_in[6];
  const float* prelu_w  = (const float*)d_in[7];
  const float* mlp_W    = (const float*)d_in[8];
  const float* mlp_b    = (const float*)d_in[9];
  const int nnodes = in_sizes[0] / 128;
  const int E = in_sizes[3];

  __half* xjp = (__half*)d_ws;
  __half* xip = xjp + (size_t)nnodes * 128;
  int* segs   = (int*)(xip + (size_t)nnodes * 128);

  hipLaunchKernelGGL(seg_bounds, dim3((NSEG + 1 + 255) / 256), dim3(256), 0, stream,
                     batch, segs, E);

  int gblocks = (nnodes + 63) / 64;
  hipLaunchKernelGGL(proj_gemm, dim3(gblocks, 2), dim3(256), 0, stream,
                     x_j, w_j, x_i, w_i, bias, xjp, xip, nnodes);

  hipLaunchKernelGGL(seg_softmax, dim3(NSEG), dim3(256), 0, stream,
                     xjp, xip, edge_idx, segs, mlp_W, prelu_w, mlp_b,
                     (float*)d_out, E);
}